// Round 13
// baseline (980.122 us; speedup 1.0000x reference)
//
#include <hip/hip_runtime.h>
#include <hip/hip_bf16.h>
#include <math.h>

using bf16 = __hip_bfloat16;
typedef __bf16 bf16x8v __attribute__((ext_vector_type(8)));
typedef float f32x4 __attribute__((ext_vector_type(4)));
typedef unsigned short ushort4v __attribute__((ext_vector_type(4)));
typedef unsigned short ushort8v __attribute__((ext_vector_type(8)));

__device__ __forceinline__ float b2f(bf16 x) { return __bfloat162float(x); }
__device__ __forceinline__ bf16 f2b(float x) { return __float2bfloat16(x); }

__device__ __forceinline__ void gload_lds16(const void* g, void* l) {
  __builtin_amdgcn_global_load_lds(
      (__attribute__((address_space(1))) void*)(void*)g,
      (__attribute__((address_space(3))) void*)l, 16, 0, 0);
}

__device__ __forceinline__ float block_sum(float v, float* buf) {
  #pragma unroll
  for (int off = 32; off > 0; off >>= 1) v += __shfl_xor(v, off);
  __syncthreads();
  if ((threadIdx.x & 63) == 0) buf[threadIdx.x >> 6] = v;
  __syncthreads();
  return buf[0] + buf[1] + buf[2] + buf[3];
}

// ------- fused weight transpose: all 12 jobs in one launch (f32 [K,N] -> bf16 [N,K]) -------
__global__ __launch_bounds__(256) void transpose_all_kernel(
    const float* __restrict__ Wq, const float* __restrict__ Wk,
    const float* __restrict__ Wv, const float* __restrict__ Wo,
    const float* __restrict__ W1, const float* __restrict__ W2,
    bf16* __restrict__ wqkvT, bf16* __restrict__ woT,
    bf16* __restrict__ w1T, bf16* __restrict__ w2T) {
  __shared__ float tile[32][33];
  const int tb = blockIdx.x;
  const float* src; bf16* dst; int K, N, t;
  if (tb < 4608) {
    const int job = tb / 576; t = tb % 576;
    const int l = job >> 2, c = job & 3;
    src = (c == 0 ? Wq : c == 1 ? Wk : c == 2 ? Wv : Wo) + (size_t)l * 768 * 768;
    dst = (c < 3) ? (wqkvT + (size_t)l * 2304 * 768 + (size_t)c * 768 * 768)
                  : (woT + (size_t)l * 768 * 768);
    K = 768; N = 768;
  } else if (tb < 9216) {
    const int r = tb - 4608; const int l = r / 2304; t = r % 2304;
    src = W1 + (size_t)l * 768 * 3072; dst = w1T + (size_t)l * 3072 * 768;
    K = 768; N = 3072;
  } else {
    const int r = tb - 9216; const int l = r / 2304; t = r % 2304;
    src = W2 + (size_t)l * 3072 * 768; dst = w2T + (size_t)l * 768 * 3072;
    K = 3072; N = 768;
  }
  const int nbx = N >> 5;
  const int bx = t % nbx, by = t / nbx;
  const int tx = threadIdx.x & 31, ty = threadIdx.x >> 5;
  #pragma unroll
  for (int i = 0; i < 4; ++i) {
    const int r = by * 32 + ty + i * 8;
    tile[ty + i * 8][tx] = src[(size_t)r * N + bx * 32 + tx];
  }
  __syncthreads();
  #pragma unroll
  for (int i = 0; i < 4; ++i) {
    const int r = bx * 32 + ty + i * 8;
    dst[(size_t)r * K + by * 32 + tx] = f2b(tile[tx][ty + i * 8]);
  }
}

__global__ __launch_bounds__(256) void biasqkv_kernel(
    const float* __restrict__ bq, const float* __restrict__ bk,
    const float* __restrict__ bv, float* __restrict__ out) {
  const int i = blockIdx.x * 256 + threadIdx.x;
  if (i >= 2 * 2304) return;
  const int l = i / 2304, n = i % 2304;
  float v = (n < 768) ? bq[l * 768 + n]
          : (n < 1536) ? bk[l * 768 + n - 768] : bv[l * 768 + n - 1536];
  out[i] = v;
}

// ---------------- conv patchify ----------------
__global__ __launch_bounds__(256) void patchify_kernel(
    const float* __restrict__ in, const float* __restrict__ w,
    const float* __restrict__ cb, bf16* __restrict__ e) {
  __shared__ float patch[8][64];
  const int tid = threadIdx.x;
  const int tok0 = blockIdx.x * 8;
  for (int idx = tid; idx < 512; idx += 256) {
    const int t = idx >> 6, p = idx & 63;
    const int tok = tok0 + t;
    const int b = tok >> 6, t2 = tok & 63, tt = t2 >> 2, ss = t2 & 3;
    const int kt = p >> 4, kf = p & 15;
    patch[t][p] = in[((size_t)b * 64 + tt * 4 + kt) * 64 + ss * 16 + kf];
  }
  __syncthreads();
  for (int i = 0; i < 3; ++i) {
    const int d = tid + i * 256;
    const float cbv = cb[d];
    float acc[8];
    #pragma unroll
    for (int t = 0; t < 8; ++t) acc[t] = cbv;
    for (int p = 0; p < 64; ++p) {
      const float wv = w[p * 768 + d];
      #pragma unroll
      for (int t = 0; t < 8; ++t) acc[t] += patch[t][p] * wv;
    }
    #pragma unroll
    for (int t = 0; t < 8; ++t) e[(size_t)(tok0 + t) * 768 + d] = f2b(acc[t]);
  }
}

// ---------------- mask + shuffle + pos-embed + LN + agg prepend ----------------
__global__ __launch_bounds__(256) void embed_kernel(
    const bf16* __restrict__ e, const float* __restrict__ randomness,
    const int* __restrict__ perm, const float* __restrict__ temp_embd,
    const float* __restrict__ spec_embd, const float* __restrict__ pls,
    const float* __restrict__ plb, const float* __restrict__ mask_tok,
    const float* __restrict__ agg_tok, bf16* __restrict__ h) {
  __shared__ float rbuf[4];
  const int row = blockIdx.x;
  const int b = row / 65, s = row % 65;
  const int tid = threadIdx.x;
  const size_t ob = (size_t)row * 768;
  if (s == 0) {
    #pragma unroll
    for (int i = 0; i < 3; ++i) { const int d = tid + i * 256; h[ob + d] = f2b(agg_tok[d]); }
    return;
  }
  const int tok = s - 1;
  const int gt = b * 64 + tok;
  const float r0 = randomness[gt * 3 + 0];
  const float r1 = randomness[gt * 3 + 1];
  const float r2 = randomness[gt * 3 + 2];
  const bool selb = (r0 <= 0.2f);
  const bool mflag = selb && (r1 <= 0.8f);
  const bool rflag = selb && (r1 > 0.8f) && (r2 <= 0.5f);
  const int src = rflag ? perm[gt] : gt;
  const int tt = tok >> 2, ss2 = tok & 3;
  float v[3]; float sum = 0.f;
  #pragma unroll
  for (int i = 0; i < 3; ++i) {
    const int d = tid + i * 256;
    const float ev = mflag ? mask_tok[d] : b2f(e[(size_t)src * 768 + d]);
    v[i] = ev + temp_embd[tt * 768 + d] + spec_embd[ss2 * 768 + d];
    sum += v[i];
  }
  const float mu = block_sum(sum, rbuf) * (1.f / 768.f);
  float q = 0.f;
  #pragma unroll
  for (int i = 0; i < 3; ++i) { const float t = v[i] - mu; q += t * t; }
  const float rstd = rsqrtf(block_sum(q, rbuf) * (1.f / 768.f) + 1e-6f);
  #pragma unroll
  for (int i = 0; i < 3; ++i) {
    const int d = tid + i * 256;
    h[ob + d] = f2b((v[i] - mu) * rstd * pls[d] + plb[d]);
  }
}

// ---------------- residual + LN ----------------
template <int F32OUT>
__global__ __launch_bounds__(256) void resln_kernel(
    const bf16* __restrict__ x, const bf16* __restrict__ y,
    const float* __restrict__ sc, const float* __restrict__ bi,
    void* __restrict__ outp) {
  __shared__ float rbuf[4];
  const int tid = threadIdx.x;
  const size_t base = (size_t)blockIdx.x * 768;
  float v[3]; float s = 0.f;
  #pragma unroll
  for (int i = 0; i < 3; ++i) {
    const int d = tid + i * 256;
    v[i] = b2f(x[base + d]) + b2f(y[base + d]);
    s += v[i];
  }
  const float mu = block_sum(s, rbuf) * (1.f / 768.f);
  float q = 0.f;
  #pragma unroll
  for (int i = 0; i < 3; ++i) { const float t = v[i] - mu; q += t * t; }
  const float rstd = rsqrtf(block_sum(q, rbuf) * (1.f / 768.f) + 1e-6f);
  #pragma unroll
  for (int i = 0; i < 3; ++i) {
    const int d = tid + i * 256;
    const float o = (v[i] - mu) * rstd * sc[d] + bi[d];
    if (F32OUT) ((float*)outp)[base + d] = o;
    else        ((bf16*)outp)[base + d] = f2b(o);
  }
}

// ===== r12 winner + bigger wave tile: BM=256, BN=128, BK=64 single-buffer =====
// C[M,N] = act(A[M,K] @ BT[N,K]^T + bias). 256 thr = 4 waves (2Mx2N), wave
// tile 128x64, acc[8][4]. Per kk: 8 A-frags + 4 B-frags -> 32 MFMA =>
// 384 B LDS-read/MFMA (-25% vs r12's 512) and B-panel staged M/256 times
// (halved re-fetch). LDS 48KB single slot: A[256][128B] + B[128][128B];
// 128B rows, swizzle LDS[r][c16]=glob[r][c16^(r&7)] via pre-swizzled source
// (HW-verified conflict-free in r12). Loop = r12's proven form: stage(t) ->
// sync(drain) -> compute(t) -> sync(WAR). 12 drains at K=768.
template <int ACT>
__global__ __launch_bounds__(256, 2) void gemm256w_kernel(
    const unsigned short* __restrict__ A, const unsigned short* __restrict__ BT,
    const float* __restrict__ bias, bf16* __restrict__ C, int N, int K, int nbn) {
  __shared__ __align__(16) char smem[49152];   // A 32KB + B 16KB

  // bijective XCD swizzle (m204)
  const int nwg = gridDim.x;
  const int orig = blockIdx.x;
  const int q8 = nwg >> 3, r8 = nwg & 7;
  const int xcd = orig & 7, lin = orig >> 3;
  const int bid = (xcd < r8 ? xcd * (q8 + 1) : r8 * (q8 + 1) + (xcd - r8) * q8) + lin;
  const int bm = bid / nbn, bn = bid % nbn;

  const int tid = threadIdx.x;
  const int w = tid >> 6, lane = tid & 63;
  const int wrow = w >> 1, wcol = w & 1;       // 2M x 2N wave grid
  const int frow = lane & 15;
  const int cg = lane >> 4;                    // 16B chunk-in-kk 0..3

  const size_t Kb = (size_t)K * 2;
  const int laneRow8 = lane >> 3;              // staging row 0..7
  const int srcCB = (((lane & 7) ^ laneRow8) << 4);  // pre-swizzled src chunk
  const char* gA = (const char*)A + ((size_t)bm * 256 + w * 64 + laneRow8) * Kb + srcCB;
  const char* gB = (const char*)BT + ((size_t)bn * 128 + w * 32 + laneRow8) * Kb + srcCB;

  f32x4 acc[8][4];
  #pragma unroll
  for (int i = 0; i < 8; ++i)
    #pragma unroll
    for (int j = 0; j < 4; ++j) acc[i][j] = f32x4{0.f, 0.f, 0.f, 0.f};

  char* sa = smem;
  char* sb = smem + 32768;

  auto stage = [&](int t) {
    const size_t kb = (size_t)t * 128;         // t*64 cols * 2B
    #pragma unroll
    for (int j = 0; j < 8; ++j)
      gload_lds16(gA + (size_t)j * 8 * Kb + kb, sa + (w * 64 + j * 8) * 128);
    #pragma unroll
    for (int j = 0; j < 4; ++j)
      gload_lds16(gB + (size_t)j * 8 * Kb + kb, sb + (w * 32 + j * 8) * 128);
  };

  auto compute = [&]() {
    #pragma unroll
    for (int kk = 0; kk < 2; ++kk) {
      bf16x8v aa[8], bb[4];
      #pragma unroll
      for (int m = 0; m < 8; ++m) {
        const int row = wrow * 128 + m * 16 + frow;
        aa[m] = *(const bf16x8v*)(sa + row * 128 + (((4 * kk + cg) ^ (row & 7)) << 4));
      }
      #pragma unroll
      for (int n = 0; n < 4; ++n) {
        const int row = wcol * 64 + n * 16 + frow;
        bb[n] = *(const bf16x8v*)(sb + row * 128 + (((4 * kk + cg) ^ (row & 7)) << 4));
      }
      __builtin_amdgcn_s_setprio(1);
      #pragma unroll
      for (int m = 0; m < 8; ++m)
        #pragma unroll
        for (int n = 0; n < 4; ++n)
          acc[m][n] = __builtin_amdgcn_mfma_f32_16x16x32_bf16(aa[m], bb[n], acc[m][n], 0, 0, 0);
      __builtin_amdgcn_s_setprio(0);
    }
  };

  const int T = K >> 6;
  for (int t = 0; t < T; ++t) {
    stage(t);
    __syncthreads();     // drains vmcnt -> tile visible
    compute();
    __syncthreads();     // WAR before next stage overwrites
  }

  // ---- epilogue: bias(+gelu), 128-row-half repack (stride 136), 16B stores ----
  bf16* cbuf = (bf16*)smem;
  float bias4[4];
  #pragma unroll
  for (int n = 0; n < 4; ++n) bias4[n] = bias[bn * 128 + wcol * 64 + n * 16 + frow];
  const int rgrp = (lane >> 4) << 2;
  #pragma unroll
  for (int half = 0; half < 2; ++half) {
    if (wrow == half) {
      #pragma unroll
      for (int mf = 0; mf < 8; ++mf)
        #pragma unroll
        for (int n = 0; n < 4; ++n) {
          const int col = wcol * 64 + n * 16 + frow;
          #pragma unroll
          for (int r = 0; r < 4; ++r) {
            float v = acc[mf][n][r] + bias4[n];
            if (ACT == 1) v = 0.5f * v * (1.0f + erff(v * 0.70710678f));
            cbuf[(mf * 16 + rgrp + r) * 136 + col] = f2b(v);
          }
        }
    }
    __syncthreads();
    #pragma unroll
    for (int jj = 0; jj < 8; ++jj) {
      const int idx = tid + jj * 256;           // 128 rows x 16 chunks
      const int rowl = idx >> 4, c = idx & 15;
      const ushort8v val = *(const ushort8v*)(cbuf + rowl * 136 + c * 8);
      *(ushort8v*)(C + ((size_t)(bm * 256 + half * 128 + rowl)) * N + (size_t)bn * 128 + c * 8) = val;
    }
    __syncthreads();
  }
}

// ---------------- MFMA attention: one block per (batch, head), 5 waves ----------------
__global__ __launch_bounds__(320) void attn_mfma_kernel(
    const bf16* __restrict__ qkv, bf16* __restrict__ ctx) {
  __shared__ __align__(16) bf16 sK[80][72];
  __shared__ __align__(16) bf16 sVt[64][104];
  __shared__ __align__(16) bf16 sP[5][16][104];
  const int b = blockIdx.x / 12, h = blockIdx.x % 12;
  const int tid = threadIdx.x;
  const int wave = tid >> 6, lane = tid & 63;
  const size_t base = ((size_t)b * 65) * 2304 + (size_t)h * 64;
  const bf16 bzero = f2b(0.f);

  for (int idx = tid; idx < 65 * 16; idx += 320) {
    const int row = idx >> 4, d4 = (idx & 15) * 4;
    const ushort4v kv = *(const ushort4v*)(qkv + base + (size_t)row * 2304 + 768 + d4);
    const ushort4v vv = *(const ushort4v*)(qkv + base + (size_t)row * 2304 + 1536 + d4);
    *(ushort4v*)&sK[row][d4] = kv;
    #pragma unroll
    for (int j = 0; j < 4; ++j) ((unsigned short*)&sVt[d4 + j][row])[0] = vv[j];
  }
  for (int idx = tid; idx < 15 * 16; idx += 320) {
    const int row = 65 + (idx >> 4), d4 = (idx & 15) * 4;
    *(ushort4v*)&sK[row][d4] = ushort4v{0, 0, 0, 0};
  }
  for (int idx = tid; idx < 64 * 31; idx += 320) {
    const int d = idx / 31, c = 65 + (idx % 31);
    sVt[d][c] = bzero;
  }
  __syncthreads();

  const int frow = lane & 15;
  const int koff = (lane >> 4) * 8;
  const int row0 = wave * 16;
  const int qrow = (row0 + frow > 64) ? 64 : (row0 + frow);
  const bf16* qptr = qkv + base + (size_t)qrow * 2304;
  const bf16x8v aq0 = *(const bf16x8v*)(qptr + koff);
  const bf16x8v aq1 = *(const bf16x8v*)(qptr + 32 + koff);

  const f32x4 z4 = {0.f, 0.f, 0.f, 0.f};
  f32x4 sacc[5];
  #pragma unroll
  for (int n = 0; n < 5; ++n) sacc[n] = z4;
  #pragma unroll
  for (int n = 0; n < 5; ++n) {
    const bf16x8v b0 = *(const bf16x8v*)&sK[n * 16 + frow][koff];
    const bf16x8v b1 = *(const bf16x8v*)&sK[n * 16 + frow][32 + koff];
    sacc[n] = __builtin_amdgcn_mfma_f32_16x16x32_bf16(aq0, b0, sacc[n], 0, 0, 0);
    sacc[n] = __builtin_amdgcn_mfma_f32_16x16x32_bf16(aq1, b1, sacc[n], 0, 0, 0);
  }

  #pragma unroll
  for (int r = 0; r < 4; ++r) {
    const int prow = ((lane >> 4) << 2) + r;
    float v[5];
    float mx = -1e30f;
    #pragma unroll
    for (int n = 0; n < 5; ++n) {
      const int col = n * 16 + frow;
      v[n] = (col < 65) ? sacc[n][r] * 0.125f : -1e30f;
      mx = fmaxf(mx, v[n]);
    }
    #pragma unroll
    for (int off = 1; off < 16; off <<= 1) mx = fmaxf(mx, __shfl_xor(mx, off));
    float sum = 0.f;
    #pragma unroll
    for (int n = 0; n < 5; ++n) { v[n] = __expf(v[n] - mx); sum += v[n]; }
    #pragma unroll
    for (int off = 1; off < 16; off <<= 1) sum += __shfl_xor(sum, off);
    const float inv = 1.f / sum;
    #pragma unroll
    for (int n = 0; n < 5; ++n)
      sP[wave][prow][n * 16 + frow] = f2b(v[n] * inv);
    sP[wave][prow][80 + frow] = bzero;
  }

  f32x4 oacc[4];
  #pragma unroll
  for (int n = 0; n < 4; ++n) oacc[n] = z4;
  #pragma unroll
  for (int kk = 0; kk < 3; ++kk) {
    const bf16x8v ap = *(const bf16x8v*)&sP[wave][frow][kk * 32 + koff];
    #pragma unroll
    for (int n = 0; n < 4; ++n) {
      const bf16x8v bv = *(const bf16x8v*)&sVt[n * 16 + frow][kk * 32 + koff];
      oacc[n] = __builtin_amdgcn_mfma_f32_16x16x32_bf16(ap, bv, oacc[n], 0, 0, 0);
    }
  }

  #pragma unroll
  for (int r = 0; r < 4; ++r) {
    const int row = row0 + ((lane >> 4) << 2) + r;
    if (row < 65) {
      bf16* op = ctx + ((size_t)b * 65 + row) * 768 + (size_t)h * 64 + frow;
      #pragma unroll
      for (int n = 0; n < 4; ++n) op[n * 16] = f2b(oacc[n][r]);
    }
  }
}

extern "C" void kernel_launch(void* const* d_in, const int* in_sizes, int n_in,
                              void* d_out, int out_size, void* d_ws, size_t ws_size,
                              hipStream_t stream) {
  (void)in_sizes; (void)n_in; (void)out_size; (void)ws_size;
  const float* inputs     = (const float*)d_in[0];
  const float* randomness = (const float*)d_in[1];
  const int*   perm       = (const int*)d_in[2];
  const float* conv_w     = (const float*)d_in[3];
  const float* conv_b     = (const float*)d_in[4];
  const float* temp_embd  = (const float*)d_in[5];
  const float* spec_embd  = (const float*)d_in[6];
  const float* pos_ln_s   = (const float*)d_in[7];
  const float* pos_ln_b   = (const float*)d_in[8];
  const float* mask_tok   = (const float*)d_in[9];
  const float* agg_tok    = (const float*)d_in[10];
  const float* Wq = (const float*)d_in[11]; const float* bq = (const float*)d_in[12];
  const float* Wk = (const float*)d_in[13]; const float* bk = (const float*)d_in[14];
  const float* Wv = (const float*)d_in[15]; const float* bv = (const float*)d_in[16];
  const float* Wo = (const float*)d_in[17]; const float* bo = (const float*)d_in[18];
  const float* ln1_s = (const float*)d_in[19]; const float* ln1_b = (const float*)d_in[20];
  const float* W1 = (const float*)d_in[21]; const float* b1 = (const float*)d_in[22];
  const float* W2 = (const float*)d_in[23]; const float* b2 = (const float*)d_in[24];
  const float* ln2_s = (const float*)d_in[25]; const float* ln2_b = (const float*)d_in[26];

  char* wsb = (char*)d_ws;
  size_t off = 0;
  auto carve = [&](size_t bytes) { char* p = wsb + off; off = (off + bytes + 255) & ~(size_t)255; return p; };
  bf16* wqkvT = (bf16*)carve((size_t)2 * 2304 * 768 * 2);
  bf16* woT   = (bf16*)carve((size_t)2 * 768 * 768 * 2);
  bf16* w1T   = (bf16*)carve((size_t)2 * 3072 * 768 * 2);
  bf16* w2T   = (bf16*)carve((size_t)2 * 768 * 3072 * 2);
  float* bqkv = (float*)carve((size_t)2 * 2304 * 4);
  bf16* ebuf  = (bf16*)carve((size_t)16640 * 768 * 2);
  bf16* hbuf  = (bf16*)carve((size_t)16640 * 768 * 2);
  bf16* qkvb  = (bf16*)carve((size_t)16640 * 2304 * 2);
  bf16* ctxb  = (bf16*)carve((size_t)16640 * 768 * 2);
  bf16* tmpb  = ebuf;
  bf16* midb  = qkvb;

  const dim3 blk(256);
  transpose_all_kernel<<<13824, blk, 0, stream>>>(Wq, Wk, Wv, Wo, W1, W2,
                                                  wqkvT, woT, w1T, w2T);
  biasqkv_kernel<<<18, blk, 0, stream>>>(bq, bk, bv, bqkv);
  patchify_kernel<<<2048, blk, 0, stream>>>(inputs, conv_w, conv_b, ebuf);
  embed_kernel<<<16640, blk, 0, stream>>>(ebuf, randomness, perm, temp_embd, spec_embd,
                                          pos_ln_s, pos_ln_b, mask_tok, agg_tok, hbuf);
  for (int l = 0; l < 2; ++l) {
    gemm256w_kernel<0><<<65 * 18, blk, 0, stream>>>(
        (const unsigned short*)hbuf, (const unsigned short*)(wqkvT + (size_t)l * 2304 * 768),
        bqkv + l * 2304, qkvb, 2304, 768, 18);
    attn_mfma_kernel<<<256 * 12, dim3(320), 0, stream>>>(qkvb, ctxb);
    gemm256w_kernel<0><<<65 * 6, blk, 0, stream>>>(
        (const unsigned short*)ctxb, (const unsigned short*)(woT + (size_t)l * 768 * 768),
        bo + l * 768, tmpb, 768, 768, 6);
    resln_kernel<0><<<16640, blk, 0, stream>>>(hbuf, tmpb, ln1_s + l * 768, ln1_b + l * 768, hbuf);
    gemm256w_kernel<1><<<65 * 24, blk, 0, stream>>>(
        (const unsigned short*)hbuf, (const unsigned short*)(w1T + (size_t)l * 3072 * 768),
        b1 + l * 3072, midb, 3072, 768, 24);
    gemm256w_kernel<0><<<65 * 6, blk, 0, stream>>>(
        (const unsigned short*)midb, (const unsigned short*)(w2T + (size_t)l * 768 * 3072),
        b2 + l * 768, tmpb, 768, 3072, 6);
    if (l == 1)
      resln_kernel<1><<<16640, blk, 0, stream>>>(hbuf, tmpb, ln2_s + l * 768, ln2_b + l * 768, d_out);
    else
      resln_kernel<0><<<16640, blk, 0, stream>>>(hbuf, tmpb, ln2_s + l * 768, ln2_b + l * 768, hbuf);
  }
}

// Round 14
// 843.167 us; speedup vs baseline: 1.1624x; 1.1624x over previous
//
#include <hip/hip_runtime.h>
#include <hip/hip_bf16.h>
#include <math.h>

using bf16 = __hip_bfloat16;
typedef __bf16 bf16x8v __attribute__((ext_vector_type(8)));
typedef float f32x4 __attribute__((ext_vector_type(4)));
typedef unsigned short ushort4v __attribute__((ext_vector_type(4)));
typedef unsigned short ushort8v __attribute__((ext_vector_type(8)));

__device__ __forceinline__ float b2f(bf16 x) { return __bfloat162float(x); }
__device__ __forceinline__ bf16 f2b(float x) { return __float2bfloat16(x); }

__device__ __forceinline__ void gload_lds16(const void* g, void* l) {
  __builtin_amdgcn_global_load_lds(
      (__attribute__((address_space(1))) void*)(void*)g,
      (__attribute__((address_space(3))) void*)l, 16, 0, 0);
}

__device__ __forceinline__ float block_sum(float v, float* buf) {
  #pragma unroll
  for (int off = 32; off > 0; off >>= 1) v += __shfl_xor(v, off);
  __syncthreads();
  if ((threadIdx.x & 63) == 0) buf[threadIdx.x >> 6] = v;
  __syncthreads();
  return buf[0] + buf[1] + buf[2] + buf[3];
}

// ------- fused weight transpose: all 12 jobs in one launch (f32 [K,N] -> bf16 [N,K]) -------
__global__ __launch_bounds__(256) void transpose_all_kernel(
    const float* __restrict__ Wq, const float* __restrict__ Wk,
    const float* __restrict__ Wv, const float* __restrict__ Wo,
    const float* __restrict__ W1, const float* __restrict__ W2,
    bf16* __restrict__ wqkvT, bf16* __restrict__ woT,
    bf16* __restrict__ w1T, bf16* __restrict__ w2T) {
  __shared__ float tile[32][33];
  const int tb = blockIdx.x;
  const float* src; bf16* dst; int K, N, t;
  if (tb < 4608) {
    const int job = tb / 576; t = tb % 576;
    const int l = job >> 2, c = job & 3;
    src = (c == 0 ? Wq : c == 1 ? Wk : c == 2 ? Wv : Wo) + (size_t)l * 768 * 768;
    dst = (c < 3) ? (wqkvT + (size_t)l * 2304 * 768 + (size_t)c * 768 * 768)
                  : (woT + (size_t)l * 768 * 768);
    K = 768; N = 768;
  } else if (tb < 9216) {
    const int r = tb - 4608; const int l = r / 2304; t = r % 2304;
    src = W1 + (size_t)l * 768 * 3072; dst = w1T + (size_t)l * 3072 * 768;
    K = 768; N = 3072;
  } else {
    const int r = tb - 9216; const int l = r / 2304; t = r % 2304;
    src = W2 + (size_t)l * 3072 * 768; dst = w2T + (size_t)l * 768 * 3072;
    K = 3072; N = 768;
  }
  const int nbx = N >> 5;
  const int bx = t % nbx, by = t / nbx;
  const int tx = threadIdx.x & 31, ty = threadIdx.x >> 5;
  #pragma unroll
  for (int i = 0; i < 4; ++i) {
    const int r = by * 32 + ty + i * 8;
    tile[ty + i * 8][tx] = src[(size_t)r * N + bx * 32 + tx];
  }
  __syncthreads();
  #pragma unroll
  for (int i = 0; i < 4; ++i) {
    const int r = bx * 32 + ty + i * 8;
    dst[(size_t)r * K + by * 32 + tx] = f2b(tile[tx][ty + i * 8]);
  }
}

__global__ __launch_bounds__(256) void biasqkv_kernel(
    const float* __restrict__ bq, const float* __restrict__ bk,
    const float* __restrict__ bv, float* __restrict__ out) {
  const int i = blockIdx.x * 256 + threadIdx.x;
  if (i >= 2 * 2304) return;
  const int l = i / 2304, n = i % 2304;
  float v = (n < 768) ? bq[l * 768 + n]
          : (n < 1536) ? bk[l * 768 + n - 768] : bv[l * 768 + n - 1536];
  out[i] = v;
}

// ---------------- conv patchify ----------------
__global__ __launch_bounds__(256) void patchify_kernel(
    const float* __restrict__ in, const float* __restrict__ w,
    const float* __restrict__ cb, bf16* __restrict__ e) {
  __shared__ float patch[8][64];
  const int tid = threadIdx.x;
  const int tok0 = blockIdx.x * 8;
  for (int idx = tid; idx < 512; idx += 256) {
    const int t = idx >> 6, p = idx & 63;
    const int tok = tok0 + t;
    const int b = tok >> 6, t2 = tok & 63, tt = t2 >> 2, ss = t2 & 3;
    const int kt = p >> 4, kf = p & 15;
    patch[t][p] = in[((size_t)b * 64 + tt * 4 + kt) * 64 + ss * 16 + kf];
  }
  __syncthreads();
  for (int i = 0; i < 3; ++i) {
    const int d = tid + i * 256;
    const float cbv = cb[d];
    float acc[8];
    #pragma unroll
    for (int t = 0; t < 8; ++t) acc[t] = cbv;
    for (int p = 0; p < 64; ++p) {
      const float wv = w[p * 768 + d];
      #pragma unroll
      for (int t = 0; t < 8; ++t) acc[t] += patch[t][p] * wv;
    }
    #pragma unroll
    for (int t = 0; t < 8; ++t) e[(size_t)(tok0 + t) * 768 + d] = f2b(acc[t]);
  }
}

// ---------------- mask + shuffle + pos-embed + LN + agg prepend ----------------
__global__ __launch_bounds__(256) void embed_kernel(
    const bf16* __restrict__ e, const float* __restrict__ randomness,
    const int* __restrict__ perm, const float* __restrict__ temp_embd,
    const float* __restrict__ spec_embd, const float* __restrict__ pls,
    const float* __restrict__ plb, const float* __restrict__ mask_tok,
    const float* __restrict__ agg_tok, bf16* __restrict__ h) {
  __shared__ float rbuf[4];
  const int row = blockIdx.x;
  const int b = row / 65, s = row % 65;
  const int tid = threadIdx.x;
  const size_t ob = (size_t)row * 768;
  if (s == 0) {
    #pragma unroll
    for (int i = 0; i < 3; ++i) { const int d = tid + i * 256; h[ob + d] = f2b(agg_tok[d]); }
    return;
  }
  const int tok = s - 1;
  const int gt = b * 64 + tok;
  const float r0 = randomness[gt * 3 + 0];
  const float r1 = randomness[gt * 3 + 1];
  const float r2 = randomness[gt * 3 + 2];
  const bool selb = (r0 <= 0.2f);
  const bool mflag = selb && (r1 <= 0.8f);
  const bool rflag = selb && (r1 > 0.8f) && (r2 <= 0.5f);
  const int src = rflag ? perm[gt] : gt;
  const int tt = tok >> 2, ss2 = tok & 3;
  float v[3]; float sum = 0.f;
  #pragma unroll
  for (int i = 0; i < 3; ++i) {
    const int d = tid + i * 256;
    const float ev = mflag ? mask_tok[d] : b2f(e[(size_t)src * 768 + d]);
    v[i] = ev + temp_embd[tt * 768 + d] + spec_embd[ss2 * 768 + d];
    sum += v[i];
  }
  const float mu = block_sum(sum, rbuf) * (1.f / 768.f);
  float q = 0.f;
  #pragma unroll
  for (int i = 0; i < 3; ++i) { const float t = v[i] - mu; q += t * t; }
  const float rstd = rsqrtf(block_sum(q, rbuf) * (1.f / 768.f) + 1e-6f);
  #pragma unroll
  for (int i = 0; i < 3; ++i) {
    const int d = tid + i * 256;
    h[ob + d] = f2b((v[i] - mu) * rstd * pls[d] + plb[d]);
  }
}

// ---------------- residual + LN ----------------
template <int F32OUT>
__global__ __launch_bounds__(256) void resln_kernel(
    const bf16* __restrict__ x, const bf16* __restrict__ y,
    const float* __restrict__ sc, const float* __restrict__ bi,
    void* __restrict__ outp) {
  __shared__ float rbuf[4];
  const int tid = threadIdx.x;
  const size_t base = (size_t)blockIdx.x * 768;
  float v[3]; float s = 0.f;
  #pragma unroll
  for (int i = 0; i < 3; ++i) {
    const int d = tid + i * 256;
    v[i] = b2f(x[base + d]) + b2f(y[base + d]);
    s += v[i];
  }
  const float mu = block_sum(s, rbuf) * (1.f / 768.f);
  float q = 0.f;
  #pragma unroll
  for (int i = 0; i < 3; ++i) { const float t = v[i] - mu; q += t * t; }
  const float rstd = rsqrtf(block_sum(q, rbuf) * (1.f / 768.f) + 1e-6f);
  #pragma unroll
  for (int i = 0; i < 3; ++i) {
    const int d = tid + i * 256;
    const float o = (v[i] - mu) * rstd * sc[d] + bi[d];
    if (F32OUT) ((float*)outp)[base + d] = o;
    else        ((bf16*)outp)[base + d] = f2b(o);
  }
}

// ===== r12 champion GEMM (verbatim structure) + fast-GELU epilogue =====
// C[M,N] = act(A[M,K] @ BT[N,K]^T + bias). 256 thr = 4 waves (2Mx2N), wave
// tile 64x64, acc[4][4]. LDS 32KB single slot = A[128][128B] + B[128][128B],
// 4 blk/CU (the decisive variable: cross-block drain covering, r12 vs r13).
// Swizzle LDS[r][c16]=glob[r][c16^(r&7)] via pre-swizzled source (0-conflict,
// HW-verified). Loop: stage(t) -> sync(drain) -> compute(t) -> sync(WAR).
// GELU: sigmoid-form tanh approx (7 VALU vs erff's ~25; overflow-safe).
template <int ACT>
__global__ __launch_bounds__(256, 4) void gemmbk64_kernel(
    const unsigned short* __restrict__ A, const unsigned short* __restrict__ BT,
    const float* __restrict__ bias, bf16* __restrict__ C, int N, int K, int nbn) {
  __shared__ __align__(16) char smem[32768];   // A 16KB + B 16KB

  // bijective XCD swizzle (m204)
  const int nwg = gridDim.x;
  const int orig = blockIdx.x;
  const int q8 = nwg >> 3, r8 = nwg & 7;
  const int xcd = orig & 7, lin = orig >> 3;
  const int bid = (xcd < r8 ? xcd * (q8 + 1) : r8 * (q8 + 1) + (xcd - r8) * q8) + lin;
  const int bm = bid / nbn, bn = bid % nbn;

  const int tid = threadIdx.x;
  const int w = tid >> 6, lane = tid & 63;
  const int wm = (w >> 1) * 64, wn = (w & 1) * 64;   // 2M x 2N wave grid
  const int frow = lane & 15;
  const int cg = lane >> 4;                          // 16B chunk-in-kk 0..3

  const size_t Kb = (size_t)K * 2;
  const int laneRow8 = lane >> 3;                    // staging row 0..7
  const int srcCB = (((lane & 7) ^ laneRow8) << 4);  // pre-swizzled src chunk
  const char* gA = (const char*)A + ((size_t)bm * 128 + w * 32 + laneRow8) * Kb + srcCB;
  const char* gB = (const char*)BT + ((size_t)bn * 128 + w * 32 + laneRow8) * Kb + srcCB;

  f32x4 acc[4][4];
  #pragma unroll
  for (int i = 0; i < 4; ++i)
    #pragma unroll
    for (int j = 0; j < 4; ++j) acc[i][j] = f32x4{0.f, 0.f, 0.f, 0.f};

  char* sa = smem;
  char* sb = smem + 16384;

  auto stage = [&](int t) {
    const size_t kb = (size_t)t * 128;               // t*64 cols * 2B
    #pragma unroll
    for (int j = 0; j < 4; ++j) {
      gload_lds16(gA + (size_t)j * 8 * Kb + kb, sa + (w * 32 + j * 8) * 128);
      gload_lds16(gB + (size_t)j * 8 * Kb + kb, sb + (w * 32 + j * 8) * 128);
    }
  };

  auto compute = [&]() {
    #pragma unroll
    for (int kk = 0; kk < 2; ++kk) {
      bf16x8v aa[4], bb[4];
      #pragma unroll
      for (int m = 0; m < 4; ++m) {
        const int row = wm + m * 16 + frow;
        aa[m] = *(const bf16x8v*)(sa + row * 128 + (((4 * kk + cg) ^ (row & 7)) << 4));
      }
      #pragma unroll
      for (int n = 0; n < 4; ++n) {
        const int row = wn + n * 16 + frow;
        bb[n] = *(const bf16x8v*)(sb + row * 128 + (((4 * kk + cg) ^ (row & 7)) << 4));
      }
      __builtin_amdgcn_s_setprio(1);
      #pragma unroll
      for (int m = 0; m < 4; ++m)
        #pragma unroll
        for (int n = 0; n < 4; ++n)
          acc[m][n] = __builtin_amdgcn_mfma_f32_16x16x32_bf16(aa[m], bb[n], acc[m][n], 0, 0, 0);
      __builtin_amdgcn_s_setprio(0);
    }
  };

  const int T = K >> 6;
  for (int t = 0; t < T; ++t) {
    stage(t);
    __syncthreads();     // drains vmcnt -> tile visible
    compute();
    __syncthreads();     // WAR: all reads done before next stage overwrites
  }

  // ---- epilogue: bias(+fast gelu), 64-row-half repack, 16B stores ----
  bf16* cbuf = (bf16*)smem;
  float bias4[4];
  #pragma unroll
  for (int n = 0; n < 4; ++n) bias4[n] = bias[bn * 128 + wn + n * 16 + frow];
  const int rgrp = (lane >> 4) << 2;
  #pragma unroll
  for (int half = 0; half < 2; ++half) {
    if ((w >> 1) == half) {
      #pragma unroll
      for (int mf = 0; mf < 4; ++mf)
        #pragma unroll
        for (int n = 0; n < 4; ++n) {
          const int col = wn + n * 16 + frow;
          #pragma unroll
          for (int r = 0; r < 4; ++r) {
            float v = acc[mf][n][r] + bias4[n];
            if (ACT == 1) {
              // gelu(x) ~= x * sigmoid(2*0.7978845608*(x + 0.044715 x^3))
              const float u = 1.5957691216f * (v + 0.044715f * v * v * v);
              v = v / (1.f + __expf(-u));   // safe at both infinities
            }
            cbuf[(mf * 16 + rgrp + r) * 136 + col] = f2b(v);
          }
        }
    }
    __syncthreads();
    #pragma unroll
    for (int jj = 0; jj < 4; ++jj) {
      const int idx = tid + jj * 256;
      const int rowl = idx >> 4, c = idx & 15;
      const ushort8v val = *(const ushort8v*)(cbuf + rowl * 136 + c * 8);
      *(ushort8v*)(C + ((size_t)(bm * 128 + half * 64 + rowl)) * N + (size_t)bn * 128 + c * 8) = val;
    }
    __syncthreads();
  }
}

// ---------------- MFMA attention: one block per (batch, head), 5 waves ----------------
__global__ __launch_bounds__(320) void attn_mfma_kernel(
    const bf16* __restrict__ qkv, bf16* __restrict__ ctx) {
  __shared__ __align__(16) bf16 sK[80][72];
  __shared__ __align__(16) bf16 sVt[64][104];
  __shared__ __align__(16) bf16 sP[5][16][104];
  const int b = blockIdx.x / 12, h = blockIdx.x % 12;
  const int tid = threadIdx.x;
  const int wave = tid >> 6, lane = tid & 63;
  const size_t base = ((size_t)b * 65) * 2304 + (size_t)h * 64;
  const bf16 bzero = f2b(0.f);

  for (int idx = tid; idx < 65 * 16; idx += 320) {
    const int row = idx >> 4, d4 = (idx & 15) * 4;
    const ushort4v kv = *(const ushort4v*)(qkv + base + (size_t)row * 2304 + 768 + d4);
    const ushort4v vv = *(const ushort4v*)(qkv + base + (size_t)row * 2304 + 1536 + d4);
    *(ushort4v*)&sK[row][d4] = kv;
    #pragma unroll
    for (int j = 0; j < 4; ++j) ((unsigned short*)&sVt[d4 + j][row])[0] = vv[j];
  }
  for (int idx = tid; idx < 15 * 16; idx += 320) {
    const int row = 65 + (idx >> 4), d4 = (idx & 15) * 4;
    *(ushort4v*)&sK[row][d4] = ushort4v{0, 0, 0, 0};
  }
  for (int idx = tid; idx < 64 * 31; idx += 320) {
    const int d = idx / 31, c = 65 + (idx % 31);
    sVt[d][c] = bzero;
  }
  __syncthreads();

  const int frow = lane & 15;
  const int koff = (lane >> 4) * 8;
  const int row0 = wave * 16;
  const int qrow = (row0 + frow > 64) ? 64 : (row0 + frow);
  const bf16* qptr = qkv + base + (size_t)qrow * 2304;
  const bf16x8v aq0 = *(const bf16x8v*)(qptr + koff);
  const bf16x8v aq1 = *(const bf16x8v*)(qptr + 32 + koff);

  const f32x4 z4 = {0.f, 0.f, 0.f, 0.f};
  f32x4 sacc[5];
  #pragma unroll
  for (int n = 0; n < 5; ++n) sacc[n] = z4;
  #pragma unroll
  for (int n = 0; n < 5; ++n) {
    const bf16x8v b0 = *(const bf16x8v*)&sK[n * 16 + frow][koff];
    const bf16x8v b1 = *(const bf16x8v*)&sK[n * 16 + frow][32 + koff];
    sacc[n] = __builtin_amdgcn_mfma_f32_16x16x32_bf16(aq0, b0, sacc[n], 0, 0, 0);
    sacc[n] = __builtin_amdgcn_mfma_f32_16x16x32_bf16(aq1, b1, sacc[n], 0, 0, 0);
  }

  #pragma unroll
  for (int r = 0; r < 4; ++r) {
    const int prow = ((lane >> 4) << 2) + r;
    float v[5];
    float mx = -1e30f;
    #pragma unroll
    for (int n = 0; n < 5; ++n) {
      const int col = n * 16 + frow;
      v[n] = (col < 65) ? sacc[n][r] * 0.125f : -1e30f;
      mx = fmaxf(mx, v[n]);
    }
    #pragma unroll
    for (int off = 1; off < 16; off <<= 1) mx = fmaxf(mx, __shfl_xor(mx, off));
    float sum = 0.f;
    #pragma unroll
    for (int n = 0; n < 5; ++n) { v[n] = __expf(v[n] - mx); sum += v[n]; }
    #pragma unroll
    for (int off = 1; off < 16; off <<= 1) sum += __shfl_xor(sum, off);
    const float inv = 1.f / sum;
    #pragma unroll
    for (int n = 0; n < 5; ++n)
      sP[wave][prow][n * 16 + frow] = f2b(v[n] * inv);
    sP[wave][prow][80 + frow] = bzero;
  }

  f32x4 oacc[4];
  #pragma unroll
  for (int n = 0; n < 4; ++n) oacc[n] = z4;
  #pragma unroll
  for (int kk = 0; kk < 3; ++kk) {
    const bf16x8v ap = *(const bf16x8v*)&sP[wave][frow][kk * 32 + koff];
    #pragma unroll
    for (int n = 0; n < 4; ++n) {
      const bf16x8v bv = *(const bf16x8v*)&sVt[n * 16 + frow][kk * 32 + koff];
      oacc[n] = __builtin_amdgcn_mfma_f32_16x16x32_bf16(ap, bv, oacc[n], 0, 0, 0);
    }
  }

  #pragma unroll
  for (int r = 0; r < 4; ++r) {
    const int row = row0 + ((lane >> 4) << 2) + r;
    if (row < 65) {
      bf16* op = ctx + ((size_t)b * 65 + row) * 768 + (size_t)h * 64 + frow;
      #pragma unroll
      for (int n = 0; n < 4; ++n) op[n * 16] = f2b(oacc[n][r]);
    }
  }
}

extern "C" void kernel_launch(void* const* d_in, const int* in_sizes, int n_in,
                              void* d_out, int out_size, void* d_ws, size_t ws_size,
                              hipStream_t stream) {
  (void)in_sizes; (void)n_in; (void)out_size; (void)ws_size;
  const float* inputs     = (const float*)d_in[0];
  const float* randomness = (const float*)d_in[1];
  const int*   perm       = (const int*)d_in[2];
  const float* conv_w     = (const float*)d_in[3];
  const float* conv_b     = (const float*)d_in[4];
  const float* temp_embd  = (const float*)d_in[5];
  const float* spec_embd  = (const float*)d_in[6];
  const float* pos_ln_s   = (const float*)d_in[7];
  const float* pos_ln_b   = (const float*)d_in[8];
  const float* mask_tok   = (const float*)d_in[9];
  const float* agg_tok    = (const float*)d_in[10];
  const float* Wq = (const float*)d_in[11]; const float* bq = (const float*)d_in[12];
  const float* Wk = (const float*)d_in[13]; const float* bk = (const float*)d_in[14];
  const float* Wv = (const float*)d_in[15]; const float* bv = (const float*)d_in[16];
  const float* Wo = (const float*)d_in[17]; const float* bo = (const float*)d_in[18];
  const float* ln1_s = (const float*)d_in[19]; const float* ln1_b = (const float*)d_in[20];
  const float* W1 = (const float*)d_in[21]; const float* b1 = (const float*)d_in[22];
  const float* W2 = (const float*)d_in[23]; const float* b2 = (const float*)d_in[24];
  const float* ln2_s = (const float*)d_in[25]; const float* ln2_b = (const float*)d_in[26];

  char* wsb = (char*)d_ws;
  size_t off = 0;
  auto carve = [&](size_t bytes) { char* p = wsb + off; off = (off + bytes + 255) & ~(size_t)255; return p; };
  bf16* wqkvT = (bf16*)carve((size_t)2 * 2304 * 768 * 2);
  bf16* woT   = (bf16*)carve((size_t)2 * 768 * 768 * 2);
  bf16* w1T   = (bf16*)carve((size_t)2 * 3072 * 768 * 2);
  bf16* w2T   = (bf16*)carve((size_t)2 * 768 * 3072 * 2);
  float* bqkv = (float*)carve((size_t)2 * 2304 * 4);
  bf16* ebuf  = (bf16*)carve((size_t)16640 * 768 * 2);
  bf16* hbuf  = (bf16*)carve((size_t)16640 * 768 * 2);
  bf16* qkvb  = (bf16*)carve((size_t)16640 * 2304 * 2);
  bf16* ctxb  = (bf16*)carve((size_t)16640 * 768 * 2);
  bf16* tmpb  = ebuf;
  bf16* midb  = qkvb;

  const dim3 blk(256);
  transpose_all_kernel<<<13824, blk, 0, stream>>>(Wq, Wk, Wv, Wo, W1, W2,
                                                  wqkvT, woT, w1T, w2T);
  biasqkv_kernel<<<18, blk, 0, stream>>>(bq, bk, bv, bqkv);
  patchify_kernel<<<2048, blk, 0, stream>>>(inputs, conv_w, conv_b, ebuf);
  embed_kernel<<<16640, blk, 0, stream>>>(ebuf, randomness, perm, temp_embd, spec_embd,
                                          pos_ln_s, pos_ln_b, mask_tok, agg_tok, hbuf);
  for (int l = 0; l < 2; ++l) {
    gemmbk64_kernel<0><<<130 * 18, blk, 0, stream>>>(
        (const unsigned short*)hbuf, (const unsigned short*)(wqkvT + (size_t)l * 2304 * 768),
        bqkv + l * 2304, qkvb, 2304, 768, 18);
    attn_mfma_kernel<<<256 * 12, dim3(320), 0, stream>>>(qkvb, ctxb);
    gemmbk64_kernel<0><<<130 * 6, blk, 0, stream>>>(
        (const unsigned short*)ctxb, (const unsigned short*)(woT + (size_t)l * 768 * 768),
        bo + l * 768, tmpb, 768, 768, 6);
    resln_kernel<0><<<16640, blk, 0, stream>>>(hbuf, tmpb, ln1_s + l * 768, ln1_b + l * 768, hbuf);
    gemmbk64_kernel<1><<<130 * 24, blk, 0, stream>>>(
        (const unsigned short*)hbuf, (const unsigned short*)(w1T + (size_t)l * 3072 * 768),
        b1 + l * 3072, midb, 3072, 768, 24);
    gemmbk64_kernel<0><<<130 * 6, blk, 0, stream>>>(
        (const unsigned short*)midb, (const unsigned short*)(w2T + (size_t)l * 768 * 3072),
        b2 + l * 768, tmpb, 768, 3072, 6);
    if (l == 1)
      resln_kernel<1><<<16640, blk, 0, stream>>>(hbuf, tmpb, ln2_s + l * 768, ln2_b + l * 768, d_out);
    else
      resln_kernel<0><<<16640, blk, 0, stream>>>(hbuf, tmpb, ln2_s + l * 768, ln2_b + l * 768, hbuf);
  }
}